// Round 1
// 394.682 us; speedup vs baseline: 1.0270x; 1.0270x over previous
//
#include <hip/hip_runtime.h>

// 3-layer LSTM, B=4096, T=336, F=12, H=50, fp32 in/out.
// MFMA: z^T = W'(gate-permuted, gate-prescaled) @ a^T via mfma_f32_16x16x32_f16.
// R = 4*unit + gate -> each lane's 4 accumulators = 4 gates of one unit ->
// lane-local c/h update; c in registers; weights in VGPRs (loaded once).
// LAYER-SPECIALIZED WAVES: 39 cells = 13 tiles x 3 layers, each wave owns 2-3
// cells of ONE layer -> reads ONE activation plane per tick.
// ROUND-6 CHANGE: dependency-split K. L1/L2 input rows become
// [h_self 0..49 | pad | h_in 64..113 | pad]; layer delay deepened to 2 ticks
// (L0 step t, L1 step t-2, L2 step t-4). The in-half (chunks 2,3) is written
// a full tick before use -> PREFETCHED into registers during the previous
// tick. Post-barrier each L1/L2 wave issues 2 of its 4 MFMAs immediately from
// prefetch regs while self-reads + next prefetch are in flight, overlapping
// the LDS burst with matrix/VALU work (round-5 bottleneck: serialized
// read->MFMA->VALU phases, tick ~2470cy vs 1460cy VALU floor).
// 1024 threads = 16 waves (4/SIMD); cells placed 9-10 per SIMD.

#define Bsz 4096
#define Tt  336
#define BT  16
#define NTH 1024

typedef _Float16 half8 __attribute__((ext_vector_type(8)));
typedef float    floatx4 __attribute__((ext_vector_type(4)));

// act0 row: 64 halfs = 8 chunks (16B). [x 0..11 | h0_self 12..61 | pad]
// act1 row: 128 halfs = 16 chunks. [h1_self 0..49 | pad | h0_in 64..113 | pad]
// act2 row: 128 halfs = 16 chunks. [h2_self 0..49 | pad | h1_in 64..113 | pad]
// XOR-chunk swizzle: chunk c of row n stored at c ^ (n & (nchunks-1)).
struct __align__(16) SMem {
  _Float16 act0[2][BT * 64];
  _Float16 act1[2][BT * 128];
  _Float16 act2[2][BT * 128];
};  // 20480 B

__device__ __forceinline__ int offA0(int n, int L) {
  return n * 64 + ((((L >> 3) ^ n) & 7) << 3) + (L & 7);
}
__device__ __forceinline__ int offA12(int n, int L) {
  return n * 128 + ((((L >> 3) ^ n) & 15) << 3) + (L & 7);
}

// z gate-prescaled: gates i,f,o hold -log2(e)*z ; gate g holds 2*log2(e)*z.
__device__ __forceinline__ float lstm_cell(floatx4 z, float& c) {
  float ei = __builtin_amdgcn_exp2f(z[0]);
  float ef = __builtin_amdgcn_exp2f(z[1]);
  float eg = __builtin_amdgcn_exp2f(z[2]);
  float eo = __builtin_amdgcn_exp2f(z[3]);
  float ig = __builtin_amdgcn_rcpf(1.f + ei);   // sigmoid(i)
  float fg = __builtin_amdgcn_rcpf(1.f + ef);   // sigmoid(f)
  float rg = __builtin_amdgcn_rcpf(1.f + eg);
  float og = __builtin_amdgcn_rcpf(1.f + eo);   // sigmoid(o)
  float gg = 1.f - 2.f * rg;                    // tanh(g)
  c = fg * c + ig * gg;
  float ec = __builtin_amdgcn_exp2f(2.885390082f * c);
  float rc = __builtin_amdgcn_rcpf(1.f + ec);
  return og * (1.f - 2.f * rc);                 // o * tanh(c)
}

// A-fragment (8 halfs) of gate-permuted, gate-prescaled weights.
// R = 4*u + g; source row g*50+u. k<bound -> Wih; bound<=k<bound+50 -> Whh.
// (Values read past the valid K range multiply a guaranteed-zero B pad.)
__device__ __forceinline__ half8 wfrag(const float* __restrict__ Wih,
                                       const float* __restrict__ Whh,
                                       int lenih, int bound, int R, int k0) {
  half8 r = {};
  int u = R >> 2, g = R & 3;
  float sc = (g == 2) ? 2.885390082f : -1.442695041f;
  if (u < 50) {
    int row = g * 50 + u;
#pragma unroll
    for (int j = 0; j < 8; ++j) {
      int k = k0 + j;
      float v = 0.f;
      if (k < bound)           v = Wih[row * lenih + k];
      else if (k < bound + 50) v = Whh[row * 50 + (k - bound)];
      r[j] = (_Float16)(sc * v);
    }
  }
  return r;
}

#define MFMA(a, b, acc) __builtin_amdgcn_mfma_f32_16x16x32_f16((a), (b), (acc), 0, 0, 0)

__global__ __launch_bounds__(NTH, 4)
void lstm_mfma_kernel(const float* __restrict__ x,
                      const float* __restrict__ Wih0, const float* __restrict__ Whh0,
                      const float* __restrict__ bih0, const float* __restrict__ bhh0,
                      const float* __restrict__ Wih1, const float* __restrict__ Whh1,
                      const float* __restrict__ bih1, const float* __restrict__ bhh1,
                      const float* __restrict__ Wih2, const float* __restrict__ Whh2,
                      const float* __restrict__ bih2, const float* __restrict__ bhh2,
                      const float* __restrict__ Wlin, const float* __restrict__ blin,
                      float* __restrict__ out) {
  __shared__ SMem sm;
  const int tid  = threadIdx.x;
  const int blk  = blockIdx.x;
  const int lane = tid & 63;
  const int w    = tid >> 6;       // wave 0..15
  const int n    = lane & 15;      // batch col / A-row in tile
  const int q    = lane >> 4;      // quad

  // ---- zero LDS (h(-1)=0 for all layers/parities, pads=0) ----
  {
    int* zp = (int*)&sm;
    for (int i = tid; i < (int)(sizeof(SMem) / 4); i += NTH) zp[i] = 0;
  }

  // ---- wave -> (layer, cells) table; SIMD k hosts waves {k,k+4,k+8,k+12},
  //      placed so each SIMD gets 9-10 cells ----
  int Lw, nc, mm3[3] = {0, 0, 0};
  switch (w) {
    case 0:  Lw = 0; nc = 3; mm3[0] = 0;  mm3[1] = 1;  mm3[2] = 2;  break;
    case 1:  Lw = 0; nc = 2; mm3[0] = 3;  mm3[1] = 4;               break;
    case 2:  Lw = 0; nc = 3; mm3[0] = 5;  mm3[1] = 6;  mm3[2] = 7;  break;
    case 3:  Lw = 0; nc = 2; mm3[0] = 8;  mm3[1] = 9;               break;
    case 4:  Lw = 1; nc = 2; mm3[0] = 0;  mm3[1] = 1;               break;
    case 5:  Lw = 1; nc = 3; mm3[0] = 2;  mm3[1] = 3;  mm3[2] = 4;  break;
    case 6:  Lw = 1; nc = 2; mm3[0] = 5;  mm3[1] = 6;               break;
    case 7:  Lw = 1; nc = 3; mm3[0] = 7;  mm3[1] = 8;  mm3[2] = 9;  break;
    case 8:  Lw = 2; nc = 3; mm3[0] = 0;  mm3[1] = 1;  mm3[2] = 2;  break;
    case 9:  Lw = 2; nc = 2; mm3[0] = 3;  mm3[1] = 4;               break;
    case 10: Lw = 2; nc = 2; mm3[0] = 5;  mm3[1] = 6;               break;
    case 11: Lw = 2; nc = 2; mm3[0] = 7;  mm3[1] = 8;               break;
    case 12: Lw = 2; nc = 2; mm3[0] = 9;  mm3[1] = 10;              break;
    case 13: Lw = 0; nc = 3; mm3[0] = 10; mm3[1] = 11; mm3[2] = 12; break;
    case 14: Lw = 1; nc = 3; mm3[0] = 10; mm3[1] = 11; mm3[2] = 12; break;
    default: Lw = 2; nc = 2; mm3[0] = 11; mm3[1] = 12;              break;
  }
  const float* Wih = (Lw == 0) ? Wih0 : ((Lw == 1) ? Wih1 : Wih2);
  const float* Whh = (Lw == 0) ? Whh0 : ((Lw == 1) ? Whh1 : Whh2);
  const float* bih = (Lw == 0) ? bih0 : ((Lw == 1) ? bih1 : bih2);
  const float* bhh = (Lw == 0) ? bhh0 : ((Lw == 1) ? bhh1 : bhh2);

  // ---- per-cell weight fragments, biases, write offsets, c-state ----
  // af[i][0..1]: self chunks (Whh for L1/L2; packed x|h for L0)
  // af[i][2..3]: input chunks (Wih for L1/L2; unused for L0)
  half8  af[3][4];
  floatx4 bia[3];
  float  cst[3] = {0.f, 0.f, 0.f};
  int    woA[3], woB[3];
  bool   uokk[3];
#pragma unroll
  for (int i = 0; i < 3; ++i) {
    bia[i] = (floatx4){0, 0, 0, 0};
#pragma unroll
    for (int kc = 0; kc < 4; ++kc) af[i][kc] = (half8){};
    int m = mm3[i];
    int u = 4 * m + q;
    int uc = (u < 50) ? u : 49;
    uokk[i] = (i < nc) && (u < 50);
    if (Lw == 0) { woA[i] = offA0 (n, 12 + uc); woB[i] = offA12(n, 64 + uc); }
    else         { woA[i] = offA12(n, uc);      woB[i] = offA12(n, 64 + uc); }
    if (i < nc) {
      int R = 16 * m + n;
      if (Lw == 0) {
#pragma unroll
        for (int kc = 0; kc < 2; ++kc)
          af[i][kc] = wfrag(Wih, Whh, 12, 12, R, kc * 32 + q * 8);
      } else {
#pragma unroll
        for (int kc = 0; kc < 2; ++kc) {
          af[i][kc]     = wfrag(Whh, Whh, 50, 50, R, kc * 32 + q * 8);  // self
          af[i][kc + 2] = wfrag(Wih, Whh, 50, 50, R, kc * 32 + q * 8);  // input
        }
      }
      if (u < 50) {
#pragma unroll
        for (int g = 0; g < 4; ++g) {
          float sc = (g == 2) ? 2.885390082f : -1.442695041f;
          bia[i][g] = sc * (bih[g * 50 + u] + bhh[g * 50 + u]);
        }
      }
    }
  }

  // ---- lane-constant LDS read offsets (halfs) ----
  const int ro0[2] = { offA0(n, q * 8), offA0(n, 32 + q * 8) };
  const int ro1[4] = { offA12(n, q * 8),      offA12(n, 32 + q * 8),    // self
                       offA12(n, 64 + q * 8), offA12(n, 96 + q * 8) };  // input

  // ---- input-fragment prefetch double-buffer (registers) ----
  half8 bpf[2][2] = {};

  // ---- x stager: tid<192 = waves 0..2 (L0 waves), 16 rows x 12 feats ----
  const int sr = (tid < 192) ? tid / 12 : 0;
  const int sf = (tid < 192) ? tid - sr * 12 : 0;
  const int sxo = offA0(sr, sf);
  const float* xp = x + ((size_t)(blk * BT + sr) * Tt) * 12 + sf;
  float xnext = 0.f;

  __syncthreads();   // zero-fill visible
  if (tid < 192) {
    sm.act0[0][sxo] = (_Float16)xp[0];   // x(0) into parity-0 buffer
    xnext = xp[12];                      // x(1)
  }
  __syncthreads();

  // Tick TAU (parity p = TAU&1): read planes [p], write planes [1-p].
  // L0 computes step TAU (TAU<=335), L1 step TAU-2 (2<=TAU<=337),
  // L2 step TAU-4 (4<=TAU<=339). L1 prefetch active 1<=TAU<=336,
  // L2 prefetch active 3<=TAU<=338. CHK=1 -> literal-TAU folds (fill/drain).
#define TICK(p, TAU, CHK)                                                  \
  {                                                                        \
    if (Lw == 0) {                                                         \
      if (!(CHK) || (TAU) <= 335) {                                        \
        half8 b0 = *(const half8*)&sm.act0[p][ro0[0]];                     \
        half8 b1 = *(const half8*)&sm.act0[p][ro0[1]];                     \
        for (int i = 0; i < 3; ++i) if (i < nc) {                          \
          floatx4 z = bia[i];                                              \
          z = MFMA(af[i][0], b0, z);                                       \
          z = MFMA(af[i][1], b1, z);                                       \
          float h = lstm_cell(z, cst[i]);                                  \
          _Float16 hh = (_Float16)h;                                       \
          if (uokk[i]) { sm.act0[1 - (p)][woA[i]] = hh;                    \
                         sm.act1[1 - (p)][woB[i]] = hh; }                  \
        }                                                                  \
      }                                                                    \
    } else if (Lw == 1) {                                                  \
      half8 b0 = {}, b1 = {};                                              \
      if (!(CHK) || ((TAU) >= 2 && (TAU) <= 337)) {                        \
        b0 = *(const half8*)&sm.act1[p][ro1[0]];                           \
        b1 = *(const half8*)&sm.act1[p][ro1[1]];                           \
      }                                                                    \
      if (!(CHK) || ((TAU) >= 1 && (TAU) <= 336)) {                        \
        bpf[1 - (p)][0] = *(const half8*)&sm.act1[p][ro1[2]];              \
        bpf[1 - (p)][1] = *(const half8*)&sm.act1[p][ro1[3]];              \
      }                                                                    \
      if (!(CHK) || ((TAU) >= 2 && (TAU) <= 337)) {                        \
        for (int i = 0; i < 3; ++i) if (i < nc) {                          \
          floatx4 z = bia[i];                                              \
          z = MFMA(af[i][2], bpf[p][0], z);                                \
          z = MFMA(af[i][3], bpf[p][1], z);                                \
          z = MFMA(af[i][0], b0, z);                                       \
          z = MFMA(af[i][1], b1, z);                                       \
          float h = lstm_cell(z, cst[i]);                                  \
          _Float16 hh = (_Float16)h;                                       \
          if (uokk[i]) { sm.act1[1 - (p)][woA[i]] = hh;                    \
                         sm.act2[1 - (p)][woB[i]] = hh; }                  \
        }                                                                  \
      }                                                                    \
    } else {                                                               \
      half8 b0 = {}, b1 = {};                                              \
      if (!(CHK) || ((TAU) >= 4 && (TAU) <= 339)) {                        \
        b0 = *(const half8*)&sm.act2[p][ro1[0]];                           \
        b1 = *(const half8*)&sm.act2[p][ro1[1]];                           \
      }                                                                    \
      if (!(CHK) || ((TAU) >= 3 && (TAU) <= 338)) {                        \
        bpf[1 - (p)][0] = *(const half8*)&sm.act2[p][ro1[2]];              \
        bpf[1 - (p)][1] = *(const half8*)&sm.act2[p][ro1[3]];              \
      }                                                                    \
      if (!(CHK) || ((TAU) >= 4 && (TAU) <= 339)) {                        \
        for (int i = 0; i < 3; ++i) if (i < nc) {                          \
          floatx4 z = bia[i];                                              \
          z = MFMA(af[i][2], bpf[p][0], z);                                \
          z = MFMA(af[i][3], bpf[p][1], z);                                \
          z = MFMA(af[i][0], b0, z);                                       \
          z = MFMA(af[i][1], b1, z);                                       \
          float h = lstm_cell(z, cst[i]);                                  \
          if (uokk[i]) sm.act2[1 - (p)][woA[i]] = (_Float16)h;             \
        }                                                                  \
      }                                                                    \
    }                                                                      \
    if (tid < 192) {                                                       \
      if ((TAU) + 1 < Tt) sm.act0[1 - (p)][sxo] = (_Float16)xnext;         \
      xnext = ((TAU) + 2 < Tt) ? xp[((TAU) + 2) * 12] : 0.f;               \
    }                                                                      \
    __syncthreads();                                                       \
  }

  // fill (literal TAU -> activity folds at compile time)
  TICK(0, 0, 1)
  TICK(1, 1, 1)
  TICK(0, 2, 1)
  TICK(1, 3, 1)
  // steady: ticks 4..335 (332 ticks, unroll-2 for literal parity)
#pragma unroll 1
  for (int t = 4; t < Tt; t += 2) {
    TICK(0, t, 0)
    TICK(1, t + 1, 0)
  }
  // drain
  TICK(0, 336, 1)
  TICK(1, 337, 1)
  TICK(0, 338, 1)
  TICK(1, 339, 1)
#undef TICK

  // ---- epilogue: out[r] = b_lin + h2(335) . W_lin ----
  // L2 step 335 ran at tick 339 (p=1) -> wrote act2[0] self-half (halfs 0..49)
  if (tid < BT) {
    float s = blin[0];
    for (int uu = 0; uu < 50; ++uu)
      s += Wlin[uu] * (float)sm.act2[0][offA12(tid, uu)];
    out[blk * BT + tid] = s;
  }
}

extern "C" void kernel_launch(void* const* d_in, const int* in_sizes, int n_in,
                              void* d_out, int out_size, void* d_ws, size_t ws_size,
                              hipStream_t stream) {
  const float* x    = (const float*)d_in[0];
  const float* Wih0 = (const float*)d_in[1];
  const float* Whh0 = (const float*)d_in[2];
  const float* bih0 = (const float*)d_in[3];
  const float* bhh0 = (const float*)d_in[4];
  const float* Wih1 = (const float*)d_in[5];
  const float* Whh1 = (const float*)d_in[6];
  const float* bih1 = (const float*)d_in[7];
  const float* bhh1 = (const float*)d_in[8];
  const float* Wih2 = (const float*)d_in[9];
  const float* Whh2 = (const float*)d_in[10];
  const float* bih2 = (const float*)d_in[11];
  const float* bhh2 = (const float*)d_in[12];
  const float* Wlin = (const float*)d_in[13];
  const float* blin = (const float*)d_in[14];
  float* outp = (float*)d_out;

  dim3 grid(Bsz / BT);   // 256 blocks, 1 per CU
  dim3 block(NTH);       // 16 waves -> 4 per SIMD
  lstm_mfma_kernel<<<grid, block, 0, stream>>>(
      x, Wih0, Whh0, bih0, bhh0, Wih1, Whh1, bih1, bhh1,
      Wih2, Whh2, bih2, bhh2, Wlin, blin, outp);
}

// Round 2
// 394.258 us; speedup vs baseline: 1.0281x; 1.0011x over previous
//
#include <hip/hip_runtime.h>

// 3-layer LSTM, B=4096, T=336, F=12, H=50, fp32 in/out.
// MFMA: z^T = W'(gate-permuted, gate-prescaled) @ a^T via mfma_f32_16x16x32_f16.
// R = 4*unit + gate -> each lane's 4 accumulators = 4 gates of one unit ->
// lane-local c/h update; c in registers; weights in VGPRs (loaded once).
// LAYER-SPECIALIZED WAVES; layer delay 2 ticks (L0 step t, L1 t-2, L2 t-4);
// input fragments register-prefetched one tick ahead (round-6).
// ROUND-7 CHANGES:
//  (a) COPY-FREE PLANES: each h written ONCE to its own layer plane. L1's
//      input MFMA reads act0 [x|h0] rows directly with zero weights on the
//      x positions; L2 reads act1 directly. h-stores 65->39 per tick,
//      LDS 20KB->12KB, no woB.
//  (b) BRANCH-FREE TICK BODIES: specialize once on nc (2 vs 3), then a
//      straight-line block of all MFMAs + all lstm_cells. Round-6 bottleneck:
//      per-cell `if (i<nc)` branches fenced the scheduler, serializing
//      MFMA-phase and VALU-phase (VALU 63% + MFMA 24% + LDS ~ adding to the
//      2400cy tick instead of overlapping). Straight-line lets the compiler
//      interleave matrix ops under the transcendental chains.
// 1024 threads = 16 waves (4/SIMD); cells placed 9-10 per SIMD.

#define Bsz 4096
#define Tt  336
#define BT  16
#define NTH 1024

typedef _Float16 half8 __attribute__((ext_vector_type(8)));
typedef float    floatx4 __attribute__((ext_vector_type(4)));

// All planes: 64-half rows = 8 chunks (16B), XOR-chunk swizzle (&7).
// act0 row: [x 0..11 | h0 12..61 | pad 62..63]
// act1 row: [h1 0..49 | pad]      act2 row: [h2 0..49 | pad]
struct __align__(16) SMem {
  _Float16 act0[2][BT * 64];
  _Float16 act1[2][BT * 64];
  _Float16 act2[2][BT * 64];
};  // 12288 B

__device__ __forceinline__ int offA(int n, int L) {
  return n * 64 + ((((L >> 3) ^ n) & 7) << 3) + (L & 7);
}

// z gate-prescaled: gates i,f,o hold -log2(e)*z ; gate g holds 2*log2(e)*z.
__device__ __forceinline__ float lstm_cell(floatx4 z, float& c) {
  float ei = __builtin_amdgcn_exp2f(z[0]);
  float ef = __builtin_amdgcn_exp2f(z[1]);
  float eg = __builtin_amdgcn_exp2f(z[2]);
  float eo = __builtin_amdgcn_exp2f(z[3]);
  float ig = __builtin_amdgcn_rcpf(1.f + ei);   // sigmoid(i)
  float fg = __builtin_amdgcn_rcpf(1.f + ef);   // sigmoid(f)
  float rg = __builtin_amdgcn_rcpf(1.f + eg);
  float og = __builtin_amdgcn_rcpf(1.f + eo);   // sigmoid(o)
  float gg = 1.f - 2.f * rg;                    // tanh(g)
  c = fg * c + ig * gg;
  float ec = __builtin_amdgcn_exp2f(2.885390082f * c);
  float rc = __builtin_amdgcn_rcpf(1.f + ec);
  return og * (1.f - 2.f * rc);                 // o * tanh(c)
}

// A-fragment (8 halfs), gate-permuted + gate-prescaled.
// k in [0,lena)          -> Wa[row*lena + k]
// k in [offb, offb+lenb) -> Wb[row*lenb + (k-offb)]
// else 0. (Zero weights cover x positions / pads.)
__device__ __forceinline__ half8 wfrag2(const float* __restrict__ Wa, int lena,
                                        const float* __restrict__ Wb, int offb,
                                        int lenb, int R, int k0) {
  half8 r = {};
  int u = R >> 2, g = R & 3;
  float sc = (g == 2) ? 2.885390082f : -1.442695041f;
  if (u < 50) {
    int row = g * 50 + u;
#pragma unroll
    for (int j = 0; j < 8; ++j) {
      int k = k0 + j;
      float v = 0.f;
      if (Wa && k < lena)                         v = Wa[row * lena + k];
      else if (Wb && k >= offb && k < offb + lenb) v = Wb[row * lenb + (k - offb)];
      r[j] = (_Float16)(sc * v);
    }
  }
  return r;
}

#define MFMA(a, b, acc) __builtin_amdgcn_mfma_f32_16x16x32_f16((a), (b), (acc), 0, 0, 0)

// Straight-line cell block, shallow (L0: 2 MFMAs/cell). NCC is a literal.
#define CELLS(NCC, b0, b1, sw)                                          \
  {                                                                     \
    floatx4 z0 = bia[0], z1 = bia[1], z2 = bia[2];                      \
    z0 = MFMA(af[0][0], b0, z0);                                        \
    z1 = MFMA(af[1][0], b0, z1);                                        \
    if (NCC == 3) z2 = MFMA(af[2][0], b0, z2);                          \
    z0 = MFMA(af[0][1], b1, z0);                                        \
    z1 = MFMA(af[1][1], b1, z1);                                        \
    if (NCC == 3) z2 = MFMA(af[2][1], b1, z2);                          \
    float h0v = lstm_cell(z0, cst[0]);                                  \
    float h1v = lstm_cell(z1, cst[1]);                                  \
    if (uokk[0]) (sw)[wo[0]] = (_Float16)h0v;                           \
    if (uokk[1]) (sw)[wo[1]] = (_Float16)h1v;                           \
    if (NCC == 3) {                                                     \
      float h2v = lstm_cell(z2, cst[2]);                                \
      if (uokk[2]) (sw)[wo[2]] = (_Float16)h2v;                         \
    }                                                                   \
  }

// Straight-line cell block, deep (L1/L2: 2 prefetched input MFMAs + 2 self).
#define CELLSD(NCC, b0, b1, pp, sw)                                     \
  {                                                                     \
    floatx4 z0 = bia[0], z1 = bia[1], z2 = bia[2];                      \
    z0 = MFMA(af[0][2], bpf[pp][0], z0);                                \
    z1 = MFMA(af[1][2], bpf[pp][0], z1);                                \
    if (NCC == 3) z2 = MFMA(af[2][2], bpf[pp][0], z2);                  \
    z0 = MFMA(af[0][3], bpf[pp][1], z0);                                \
    z1 = MFMA(af[1][3], bpf[pp][1], z1);                                \
    if (NCC == 3) z2 = MFMA(af[2][3], bpf[pp][1], z2);                  \
    z0 = MFMA(af[0][0], b0, z0);                                        \
    z1 = MFMA(af[1][0], b0, z1);                                        \
    if (NCC == 3) z2 = MFMA(af[2][0], b0, z2);                          \
    z0 = MFMA(af[0][1], b1, z0);                                        \
    z1 = MFMA(af[1][1], b1, z1);                                        \
    if (NCC == 3) z2 = MFMA(af[2][1], b1, z2);                          \
    float h0v = lstm_cell(z0, cst[0]);                                  \
    float h1v = lstm_cell(z1, cst[1]);                                  \
    if (uokk[0]) (sw)[wo[0]] = (_Float16)h0v;                           \
    if (uokk[1]) (sw)[wo[1]] = (_Float16)h1v;                           \
    if (NCC == 3) {                                                     \
      float h2v = lstm_cell(z2, cst[2]);                                \
      if (uokk[2]) (sw)[wo[2]] = (_Float16)h2v;                         \
    }                                                                   \
  }

__global__ __launch_bounds__(NTH, 4)
void lstm_mfma_kernel(const float* __restrict__ x,
                      const float* __restrict__ Wih0, const float* __restrict__ Whh0,
                      const float* __restrict__ bih0, const float* __restrict__ bhh0,
                      const float* __restrict__ Wih1, const float* __restrict__ Whh1,
                      const float* __restrict__ bih1, const float* __restrict__ bhh1,
                      const float* __restrict__ Wih2, const float* __restrict__ Whh2,
                      const float* __restrict__ bih2, const float* __restrict__ bhh2,
                      const float* __restrict__ Wlin, const float* __restrict__ blin,
                      float* __restrict__ out) {
  __shared__ SMem sm;
  const int tid  = threadIdx.x;
  const int blk  = blockIdx.x;
  const int lane = tid & 63;
  const int w    = tid >> 6;       // wave 0..15
  const int n    = lane & 15;      // batch col / A-row in tile
  const int q    = lane >> 4;      // quad

  // ---- zero LDS (h(-1)=0 for all layers/parities, pads=0) ----
  {
    int* zp = (int*)&sm;
    for (int i = tid; i < (int)(sizeof(SMem) / 4); i += NTH) zp[i] = 0;
  }

  // ---- wave -> (layer, cells) table; SIMD k hosts waves {k,k+4,k+8,k+12},
  //      placed so each SIMD gets 9-10 cells ----
  int Lw, nc, mm3[3] = {0, 0, 0};
  switch (w) {
    case 0:  Lw = 0; nc = 3; mm3[0] = 0;  mm3[1] = 1;  mm3[2] = 2;  break;
    case 1:  Lw = 0; nc = 2; mm3[0] = 3;  mm3[1] = 4;               break;
    case 2:  Lw = 0; nc = 3; mm3[0] = 5;  mm3[1] = 6;  mm3[2] = 7;  break;
    case 3:  Lw = 0; nc = 2; mm3[0] = 8;  mm3[1] = 9;               break;
    case 4:  Lw = 1; nc = 2; mm3[0] = 0;  mm3[1] = 1;               break;
    case 5:  Lw = 1; nc = 3; mm3[0] = 2;  mm3[1] = 3;  mm3[2] = 4;  break;
    case 6:  Lw = 1; nc = 2; mm3[0] = 5;  mm3[1] = 6;               break;
    case 7:  Lw = 1; nc = 3; mm3[0] = 7;  mm3[1] = 8;  mm3[2] = 9;  break;
    case 8:  Lw = 2; nc = 3; mm3[0] = 0;  mm3[1] = 1;  mm3[2] = 2;  break;
    case 9:  Lw = 2; nc = 2; mm3[0] = 3;  mm3[1] = 4;               break;
    case 10: Lw = 2; nc = 2; mm3[0] = 5;  mm3[1] = 6;               break;
    case 11: Lw = 2; nc = 2; mm3[0] = 7;  mm3[1] = 8;               break;
    case 12: Lw = 2; nc = 2; mm3[0] = 9;  mm3[1] = 10;              break;
    case 13: Lw = 0; nc = 3; mm3[0] = 10; mm3[1] = 11; mm3[2] = 12; break;
    case 14: Lw = 1; nc = 3; mm3[0] = 10; mm3[1] = 11; mm3[2] = 12; break;
    default: Lw = 2; nc = 2; mm3[0] = 11; mm3[1] = 12;              break;
  }
  const float* Wih = (Lw == 0) ? Wih0 : ((Lw == 1) ? Wih1 : Wih2);
  const float* Whh = (Lw == 0) ? Whh0 : ((Lw == 1) ? Whh1 : Whh2);
  const float* bih = (Lw == 0) ? bih0 : ((Lw == 1) ? bih1 : bih2);
  const float* bhh = (Lw == 0) ? bhh0 : ((Lw == 1) ? bhh1 : bhh2);

  // ---- per-cell weight fragments, biases, write offsets, c-state ----
  // af[i][0..1]: self chunks (k 0..63 of own plane rows)
  //   L0: [Wih0 | Whh0] packed.  L1/L2: Whh, k>=50 -> 0.
  // af[i][2..3]: input chunks (k 0..63 of producer plane rows)
  //   L1: k in [12,62) -> Wih1 (x positions zero-weighted). L2: k<50 -> Wih2.
  half8  af[3][4];
  floatx4 bia[3];
  float  cst[3] = {0.f, 0.f, 0.f};
  int    wo[3];
  bool   uokk[3];
#pragma unroll
  for (int i = 0; i < 3; ++i) {
    bia[i] = (floatx4){0, 0, 0, 0};
#pragma unroll
    for (int kc = 0; kc < 4; ++kc) af[i][kc] = (half8){};
    int m = mm3[i];
    int u = 4 * m + q;
    int uc = (u < 50) ? u : 49;
    uokk[i] = (i < nc) && (u < 50);
    wo[i] = (Lw == 0) ? offA(n, 12 + uc) : offA(n, uc);
    if (i < nc) {
      int R = 16 * m + n;
      if (Lw == 0) {
#pragma unroll
        for (int kc = 0; kc < 2; ++kc)
          af[i][kc] = wfrag2(Wih, 12, Whh, 12, 50, R, kc * 32 + q * 8);
      } else {
#pragma unroll
        for (int kc = 0; kc < 2; ++kc) {
          af[i][kc] = wfrag2(Whh, 50, nullptr, 0, 0, R, kc * 32 + q * 8); // self
          af[i][kc + 2] = (Lw == 1)
              ? wfrag2(nullptr, 0, Wih, 12, 50, R, kc * 32 + q * 8)       // in L1
              : wfrag2(Wih, 50, nullptr, 0, 0, R, kc * 32 + q * 8);       // in L2
        }
      }
      if (u < 50) {
#pragma unroll
        for (int g = 0; g < 4; ++g) {
          float sc = (g == 2) ? 2.885390082f : -1.442695041f;
          bia[i][g] = sc * (bih[g * 50 + u] + bhh[g * 50 + u]);
        }
      }
    }
  }

  // ---- lane-constant LDS read offsets (halfs; all planes 64-half rows) ----
  const int ro[2] = { offA(n, q * 8), offA(n, 32 + q * 8) };

  // ---- input-fragment prefetch double-buffer (registers) ----
  half8 bpf[2][2] = {};

  // ---- x stager: tid<192 = waves 0..2 (L0 waves), 16 rows x 12 feats ----
  const int sr = (tid < 192) ? tid / 12 : 0;
  const int sf = (tid < 192) ? tid - sr * 12 : 0;
  const int sxo = offA(sr, sf);
  const float* xp = x + ((size_t)(blk * BT + sr) * Tt) * 12 + sf;
  float xnext = 0.f;

  __syncthreads();   // zero-fill visible
  if (tid < 192) {
    sm.act0[0][sxo] = (_Float16)xp[0];   // x(0) into parity-0 buffer
    xnext = xp[12];                      // x(1)
  }
  __syncthreads();

  // Tick TAU (parity p = TAU&1): read planes [p], write planes [1-p].
  // L0 computes step TAU (TAU<=335), L1 step TAU-2 (2<=TAU<=337),
  // L2 step TAU-4 (4<=TAU<=339). L1 prefetch (from act0) active 1<=TAU<=336,
  // L2 prefetch (from act1) active 3<=TAU<=338. CHK=1 -> literal-TAU folds.
#define TICK(p, TAU, CHK)                                                  \
  {                                                                        \
    if (Lw == 0) {                                                         \
      if (!(CHK) || (TAU) <= 335) {                                        \
        half8 b0 = *(const half8*)&sm.act0[p][ro[0]];                      \
        half8 b1 = *(const half8*)&sm.act0[p][ro[1]];                      \
        _Float16* sw = &sm.act0[1 - (p)][0];                               \
        if (nc == 3) CELLS(3, b0, b1, sw) else CELLS(2, b0, b1, sw)        \
      }                                                                    \
    } else if (Lw == 1) {                                                  \
      half8 b0 = {}, b1 = {};                                              \
      if (!(CHK) || ((TAU) >= 2 && (TAU) <= 337)) {                        \
        b0 = *(const half8*)&sm.act1[p][ro[0]];                            \
        b1 = *(const half8*)&sm.act1[p][ro[1]];                            \
      }                                                                    \
      if (!(CHK) || ((TAU) >= 1 && (TAU) <= 336)) {                        \
        bpf[1 - (p)][0] = *(const half8*)&sm.act0[p][ro[0]];               \
        bpf[1 - (p)][1] = *(const half8*)&sm.act0[p][ro[1]];               \
      }                                                                    \
      if (!(CHK) || ((TAU) >= 2 && (TAU) <= 337)) {                        \
        _Float16* sw = &sm.act1[1 - (p)][0];                               \
        if (nc == 3) CELLSD(3, b0, b1, p, sw) else CELLSD(2, b0, b1, p, sw)\
      }                                                                    \
    } else {                                                               \
      half8 b0 = {}, b1 = {};                                              \
      if (!(CHK) || ((TAU) >= 4 && (TAU) <= 339)) {                        \
        b0 = *(const half8*)&sm.act2[p][ro[0]];                            \
        b1 = *(const half8*)&sm.act2[p][ro[1]];                            \
      }                                                                    \
      if (!(CHK) || ((TAU) >= 3 && (TAU) <= 338)) {                        \
        bpf[1 - (p)][0] = *(const half8*)&sm.act1[p][ro[0]];               \
        bpf[1 - (p)][1] = *(const half8*)&sm.act1[p][ro[1]];               \
      }                                                                    \
      if (!(CHK) || ((TAU) >= 4 && (TAU) <= 339)) {                        \
        _Float16* sw = &sm.act2[1 - (p)][0];                               \
        if (nc == 3) CELLSD(3, b0, b1, p, sw) else CELLSD(2, b0, b1, p, sw)\
      }                                                                    \
    }                                                                      \
    if (tid < 192) {                                                       \
      if ((TAU) + 1 < Tt) sm.act0[1 - (p)][sxo] = (_Float16)xnext;         \
      xnext = ((TAU) + 2 < Tt) ? xp[((TAU) + 2) * 12] : 0.f;               \
    }                                                                      \
    __syncthreads();                                                       \
  }

  // fill (literal TAU -> activity folds at compile time)
  TICK(0, 0, 1)
  TICK(1, 1, 1)
  TICK(0, 2, 1)
  TICK(1, 3, 1)
  // steady: ticks 4..335 (332 ticks, unroll-2 for literal parity)
#pragma unroll 1
  for (int t = 4; t < Tt; t += 2) {
    TICK(0, t, 0)
    TICK(1, t + 1, 0)
  }
  // drain
  TICK(0, 336, 1)
  TICK(1, 337, 1)
  TICK(0, 338, 1)
  TICK(1, 339, 1)
#undef TICK

  // ---- epilogue: out[r] = b_lin + h2(335) . W_lin ----
  // L2 step 335 ran at tick 339 (p=1) -> wrote act2[0] (halfs 0..49)
  if (tid < BT) {
    float s = blin[0];
    for (int uu = 0; uu < 50; ++uu)
      s += Wlin[uu] * (float)sm.act2[0][offA(tid, uu)];
    out[blk * BT + tid] = s;
  }
}

extern "C" void kernel_launch(void* const* d_in, const int* in_sizes, int n_in,
                              void* d_out, int out_size, void* d_ws, size_t ws_size,
                              hipStream_t stream) {
  const float* x    = (const float*)d_in[0];
  const float* Wih0 = (const float*)d_in[1];
  const float* Whh0 = (const float*)d_in[2];
  const float* bih0 = (const float*)d_in[3];
  const float* bhh0 = (const float*)d_in[4];
  const float* Wih1 = (const float*)d_in[5];
  const float* Whh1 = (const float*)d_in[6];
  const float* bih1 = (const float*)d_in[7];
  const float* bhh1 = (const float*)d_in[8];
  const float* Wih2 = (const float*)d_in[9];
  const float* Whh2 = (const float*)d_in[10];
  const float* bih2 = (const float*)d_in[11];
  const float* bhh2 = (const float*)d_in[12];
  const float* Wlin = (const float*)d_in[13];
  const float* blin = (const float*)d_in[14];
  float* outp = (float*)d_out;

  dim3 grid(Bsz / BT);   // 256 blocks, 1 per CU
  dim3 block(NTH);       // 16 waves -> 4 per SIMD
  lstm_mfma_kernel<<<grid, block, 0, stream>>>(
      x, Wih0, Whh0, bih0, bhh0, Wih1, Whh1, bih1, bhh1,
      Wih2, Whh2, bih2, bhh2, Wlin, blin, outp);
}